// Round 5
// baseline (208.243 us; speedup 1.0000x reference)
//
#include <hip/hip_runtime.h>
#include <hip/hip_bf16.h>
#include <cstdint>
#include <cstddef>

// AFT forward, MI355X. Pipeline (5 dispatches):
//  1. prep   : data f32->bf16 | P=exp(pos_bias) bf16 | W_qkv^T bf16 | W_out^T bf16
//  2. GEMM_q : q f32 [4096][1024] = data_bf @ Wq^T + b_q          (k_gemm)
//  3. GEMM_kv: per (d-tile, t-tile, b): k^T & v^T tiles together ->
//              epilogue writes BndT bf16 [8192][1024] num/den interleaved
//              (rows rr=((r>>4)<<5)+(r&15) num, rr+16 den; r=b*1024+d; cols=t)
//  4. GEMM2f : Y bf16 [t*4096+r] = sigmoid(q)*[P@EKV]/[P@EK]      (fused epilogue)
//  5. GEMM3  : out f32 [4096][1024] = Y @ W_out^T + b_out         (k_gemm)
// GEMM = m97 structure: 128x128 tile, BK=32, 4 waves, mfma_f32_16x16x32_bf16,
// global_load_lds width-16 staging, linear LDS. Workspace peak 50 MB.

typedef __bf16 bf16_t;
typedef __attribute__((ext_vector_type(8))) __bf16 bf16x8;
typedef __attribute__((ext_vector_type(4))) __bf16 bf16x4;
typedef __attribute__((ext_vector_type(4))) float floatx4;

#define T_DIM 1024
#define B_DIM 4
#define D_DIM 1024
#define R_DIM (T_DIM * B_DIM)   // 4096
#define N_QKV (3 * D_DIM)       // 3072
#define N_ND  (2 * R_DIM)       // 8192

// ---------------- prep: all input conversions in one dispatch ----------------
// blocks [0,4096)        : data f32 -> bf16 (1024 elems/block)
// blocks [4096,5120)     : P = exp(pos_bias) -> bf16
// blocks [5120,8192)     : tconv W_qkv [1024][3072] -> WqkvT [3072][1024]
// blocks [8192,9216)     : tconv W_out [1024][1024] -> WoutT [1024][1024]
__global__ void k_prep(const float* __restrict__ data, const float* __restrict__ pos_bias,
                       const float* __restrict__ W_qkv, const float* __restrict__ W_out,
                       bf16_t* __restrict__ data_bf, bf16_t* __restrict__ P_bf,
                       bf16_t* __restrict__ WqkvT, bf16_t* __restrict__ WoutT) {
    __shared__ float s[32][33];
    const int bid = blockIdx.x, tid = threadIdx.x;
    if (bid < 5120) {
        const float* in = (bid < 4096) ? data : pos_bias;
        bf16_t* out = (bid < 4096) ? data_bf : P_bf;
        int bb = (bid < 4096) ? bid : bid - 4096;
        int do_exp = (bid >= 4096);
        int i = (bb * 256 + tid) * 4;
        float4 v = *reinterpret_cast<const float4*>(in + i);
        bf16x4 o;
        if (do_exp) {
            o[0] = (bf16_t)__expf(v.x); o[1] = (bf16_t)__expf(v.y);
            o[2] = (bf16_t)__expf(v.z); o[3] = (bf16_t)__expf(v.w);
        } else {
            o[0] = (bf16_t)v.x; o[1] = (bf16_t)v.y;
            o[2] = (bf16_t)v.z; o[3] = (bf16_t)v.w;
        }
        *reinterpret_cast<bf16x4*>(out + i) = o;
    } else {
        const float* in; bf16_t* out; int K, N, idx;
        if (bid < 8192) { in = W_qkv; out = WqkvT; K = D_DIM; N = N_QKV; idx = bid - 5120; }
        else            { in = W_out; out = WoutT; K = D_DIM; N = D_DIM; idx = bid - 8192; }
        int nt = N / 32;
        int n0 = (idx % nt) * 32, k0 = (idx / nt) * 32;
        int tx = tid & 31, ty = tid >> 5;  // 32 x 8
#pragma unroll
        for (int i = 0; i < 4; ++i)
            s[ty + i * 8][tx] = in[(size_t)(k0 + ty + i * 8) * N + n0 + tx];
        __syncthreads();
#pragma unroll
        for (int i = 0; i < 4; ++i)
            out[(size_t)(n0 + ty + i * 8) * K + k0 + tx] = (bf16_t)s[tx][ty + i * 8];
    }
}

// ---------------- GEMM: C[M][N] = A[M][K] @ BT[N][K]^T (+bias) ----------------
__global__ __launch_bounds__(256)
void k_gemm(const bf16_t* __restrict__ A, const bf16_t* __restrict__ BT,
            const float* __restrict__ bias, float* __restrict__ C,
            int M, int N, int K) {
    __shared__ __align__(16) bf16_t As[128 * 32];
    __shared__ __align__(16) bf16_t Bs[128 * 32];
    const int tid = threadIdx.x;
    const int wid = tid >> 6, lane = tid & 63;
    const int wm = wid >> 1, wn = wid & 1;
    const int row0 = blockIdx.x * 128, col0 = blockIdx.y * 128;

    floatx4 acc[4][4];
#pragma unroll
    for (int m = 0; m < 4; ++m)
#pragma unroll
        for (int n = 0; n < 4; ++n) acc[m][n] = (floatx4){0.f, 0.f, 0.f, 0.f};

    const int lr = lane & 15;
    const int kq = (lane >> 4) * 8;
    const int e0 = wid * 1024 + lane * 8;
    const int ra0 = e0 >> 5, kk0 = e0 & 31;
    const int ra1 = (e0 + 512) >> 5, kk1 = (e0 + 512) & 31;

    const bf16_t* Ab = A + (size_t)row0 * K;
    const bf16_t* Bb = BT + (size_t)col0 * K;

    for (int kt = 0; kt < K; kt += 32) {
        __syncthreads();
        __builtin_amdgcn_global_load_lds(
            (const __attribute__((address_space(1))) void*)(Ab + (size_t)ra0 * K + kt + kk0),
            (__attribute__((address_space(3))) void*)(As + wid * 1024), 16, 0, 0);
        __builtin_amdgcn_global_load_lds(
            (const __attribute__((address_space(1))) void*)(Ab + (size_t)ra1 * K + kt + kk1),
            (__attribute__((address_space(3))) void*)(As + wid * 1024 + 512), 16, 0, 0);
        __builtin_amdgcn_global_load_lds(
            (const __attribute__((address_space(1))) void*)(Bb + (size_t)ra0 * K + kt + kk0),
            (__attribute__((address_space(3))) void*)(Bs + wid * 1024), 16, 0, 0);
        __builtin_amdgcn_global_load_lds(
            (const __attribute__((address_space(1))) void*)(Bb + (size_t)ra1 * K + kt + kk1),
            (__attribute__((address_space(3))) void*)(Bs + wid * 1024 + 512), 16, 0, 0);
        __syncthreads();

        bf16x8 af[4], bfr[4];
#pragma unroll
        for (int m = 0; m < 4; ++m)
            af[m] = *reinterpret_cast<const bf16x8*>(As + (wm * 64 + m * 16 + lr) * 32 + kq);
#pragma unroll
        for (int n = 0; n < 4; ++n)
            bfr[n] = *reinterpret_cast<const bf16x8*>(Bs + (wn * 64 + n * 16 + lr) * 32 + kq);
#pragma unroll
        for (int m = 0; m < 4; ++m)
#pragma unroll
            for (int n = 0; n < 4; ++n)
                acc[m][n] = __builtin_amdgcn_mfma_f32_16x16x32_bf16(af[m], bfr[n], acc[m][n], 0, 0, 0);
    }

    const int lg = lane >> 4;
#pragma unroll
    for (int n = 0; n < 4; ++n) {
        int col = col0 + wn * 64 + n * 16 + lr;
        float bv = bias ? bias[col] : 0.0f;
#pragma unroll
        for (int m = 0; m < 4; ++m) {
            int row = row0 + wm * 64 + m * 16 + lg * 4;
            float* Cp = C + (size_t)row * N + col;
#pragma unroll
            for (int j = 0; j < 4; ++j) Cp[(size_t)j * N] = acc[m][n][j] + bv;
        }
    }
}

// ---------------- GEMM_kv: k^T & v^T tiles -> BndT num/den directly ----------------
// Block (bx=d-tile, by=t-tile, bz=b). A_k = WqkvT rows 1024+d, A_v = rows 2048+d,
// B^T[t][din] = data_bf row 4t+b. C layout [d][t]. Epilogue: e=exp(k), writes
// BndT[rr][t]=e*v (num), BndT[rr+16][t]=e (den), rr=((r>>4)<<5)+(r&15), r=b*1024+d.
__global__ __launch_bounds__(256)
void k_gemm_kv(const bf16_t* __restrict__ WqkvT, const bf16_t* __restrict__ data_bf,
               bf16_t* __restrict__ BndT) {
    const int K = D_DIM;
    __shared__ __align__(16) bf16_t Aks[128 * 32];
    __shared__ __align__(16) bf16_t Avs[128 * 32];
    __shared__ __align__(16) bf16_t Bs[128 * 32];
    const int tid = threadIdx.x;
    const int wid = tid >> 6, lane = tid & 63;
    const int wm = wid >> 1, wn = wid & 1;
    const int row0 = blockIdx.x * 128;   // d
    const int col0 = blockIdx.y * 128;   // t
    const int b = blockIdx.z;

    floatx4 ack[4][4], acv[4][4];
#pragma unroll
    for (int m = 0; m < 4; ++m)
#pragma unroll
        for (int n = 0; n < 4; ++n) {
            ack[m][n] = (floatx4){0.f, 0.f, 0.f, 0.f};
            acv[m][n] = (floatx4){0.f, 0.f, 0.f, 0.f};
        }

    const int lr = lane & 15;
    const int kq = (lane >> 4) * 8;
    const int e0 = wid * 1024 + lane * 8;
    const int ra0 = e0 >> 5, kk0 = e0 & 31;
    const int ra1 = (e0 + 512) >> 5, kk1 = (e0 + 512) & 31;

    const bf16_t* Akb = WqkvT + (size_t)(D_DIM + row0) * K;       // k^T weight rows
    const bf16_t* Avb = WqkvT + (size_t)(2 * D_DIM + row0) * K;   // v^T weight rows
    // B rows: global data row = (col0 + ra)*4 + b
    const size_t bg0 = ((size_t)(col0 + ra0) * 4 + b) * D_DIM;
    const size_t bg1 = ((size_t)(col0 + ra1) * 4 + b) * D_DIM;

    for (int kt = 0; kt < K; kt += 32) {
        __syncthreads();
        __builtin_amdgcn_global_load_lds(
            (const __attribute__((address_space(1))) void*)(Akb + (size_t)ra0 * K + kt + kk0),
            (__attribute__((address_space(3))) void*)(Aks + wid * 1024), 16, 0, 0);
        __builtin_amdgcn_global_load_lds(
            (const __attribute__((address_space(1))) void*)(Akb + (size_t)ra1 * K + kt + kk1),
            (__attribute__((address_space(3))) void*)(Aks + wid * 1024 + 512), 16, 0, 0);
        __builtin_amdgcn_global_load_lds(
            (const __attribute__((address_space(1))) void*)(Avb + (size_t)ra0 * K + kt + kk0),
            (__attribute__((address_space(3))) void*)(Avs + wid * 1024), 16, 0, 0);
        __builtin_amdgcn_global_load_lds(
            (const __attribute__((address_space(1))) void*)(Avb + (size_t)ra1 * K + kt + kk1),
            (__attribute__((address_space(3))) void*)(Avs + wid * 1024 + 512), 16, 0, 0);
        __builtin_amdgcn_global_load_lds(
            (const __attribute__((address_space(1))) void*)(data_bf + bg0 + kt + kk0),
            (__attribute__((address_space(3))) void*)(Bs + wid * 1024), 16, 0, 0);
        __builtin_amdgcn_global_load_lds(
            (const __attribute__((address_space(1))) void*)(data_bf + bg1 + kt + kk1),
            (__attribute__((address_space(3))) void*)(Bs + wid * 1024 + 512), 16, 0, 0);
        __syncthreads();

        bf16x8 afk[4], afv[4], bfr[4];
#pragma unroll
        for (int m = 0; m < 4; ++m) {
            afk[m] = *reinterpret_cast<const bf16x8*>(Aks + (wm * 64 + m * 16 + lr) * 32 + kq);
            afv[m] = *reinterpret_cast<const bf16x8*>(Avs + (wm * 64 + m * 16 + lr) * 32 + kq);
        }
#pragma unroll
        for (int n = 0; n < 4; ++n)
            bfr[n] = *reinterpret_cast<const bf16x8*>(Bs + (wn * 64 + n * 16 + lr) * 32 + kq);
#pragma unroll
        for (int m = 0; m < 4; ++m)
#pragma unroll
            for (int n = 0; n < 4; ++n) {
                ack[m][n] = __builtin_amdgcn_mfma_f32_16x16x32_bf16(afk[m], bfr[n], ack[m][n], 0, 0, 0);
                acv[m][n] = __builtin_amdgcn_mfma_f32_16x16x32_bf16(afv[m], bfr[n], acv[m][n], 0, 0, 0);
            }
    }

    const int lg = lane >> 4;
#pragma unroll
    for (int n = 0; n < 4; ++n) {
        int t = col0 + wn * 64 + n * 16 + lr;
#pragma unroll
        for (int m = 0; m < 4; ++m) {
            int dbase = row0 + wm * 64 + m * 16 + lg * 4;
#pragma unroll
            for (int j = 0; j < 4; ++j) {
                int d = dbase + j;
                int r = b * D_DIM + d;
                int rr = ((r >> 4) << 5) + (r & 15);
                float e = __expf(ack[m][n][j]);
                BndT[(size_t)rr * T_DIM + t] = (bf16_t)(e * acv[m][n][j]);   // num
                BndT[(size_t)(rr + 16) * T_DIM + t] = (bf16_t)e;             // den
            }
        }
    }
}

// ---------------- GEMM2 fused: Y = sigmoid(q) * (P@EKV)/(P@EK) ----------------
// M=1024 (t), N=8192 (interleaved num/den), K=1024. Fragment pairs (n=2p, 2p+1)
// carry num/den for the same 16 columns. q flat layout: q[t*4096 + r].
__global__ __launch_bounds__(256)
void k_gemm_aft(const bf16_t* __restrict__ A, const bf16_t* __restrict__ BT,
                const float* __restrict__ q, bf16_t* __restrict__ Y) {
    const int K = T_DIM;
    __shared__ __align__(16) bf16_t As[128 * 32];
    __shared__ __align__(16) bf16_t Bs[128 * 32];
    const int tid = threadIdx.x;
    const int wid = tid >> 6, lane = tid & 63;
    const int wm = wid >> 1, wn = wid & 1;
    const int row0 = blockIdx.x * 128, col0 = blockIdx.y * 128;

    floatx4 acc[4][4];
#pragma unroll
    for (int m = 0; m < 4; ++m)
#pragma unroll
        for (int n = 0; n < 4; ++n) acc[m][n] = (floatx4){0.f, 0.f, 0.f, 0.f};

    const int lr = lane & 15;
    const int kq = (lane >> 4) * 8;
    const int e0 = wid * 1024 + lane * 8;
    const int ra0 = e0 >> 5, kk0 = e0 & 31;
    const int ra1 = (e0 + 512) >> 5, kk1 = (e0 + 512) & 31;

    const bf16_t* Ab = A + (size_t)row0 * K;
    const bf16_t* Bb = BT + (size_t)col0 * K;

    for (int kt = 0; kt < K; kt += 32) {
        __syncthreads();
        __builtin_amdgcn_global_load_lds(
            (const __attribute__((address_space(1))) void*)(Ab + (size_t)ra0 * K + kt + kk0),
            (__attribute__((address_space(3))) void*)(As + wid * 1024), 16, 0, 0);
        __builtin_amdgcn_global_load_lds(
            (const __attribute__((address_space(1))) void*)(Ab + (size_t)ra1 * K + kt + kk1),
            (__attribute__((address_space(3))) void*)(As + wid * 1024 + 512), 16, 0, 0);
        __builtin_amdgcn_global_load_lds(
            (const __attribute__((address_space(1))) void*)(Bb + (size_t)ra0 * K + kt + kk0),
            (__attribute__((address_space(3))) void*)(Bs + wid * 1024), 16, 0, 0);
        __builtin_amdgcn_global_load_lds(
            (const __attribute__((address_space(1))) void*)(Bb + (size_t)ra1 * K + kt + kk1),
            (__attribute__((address_space(3))) void*)(Bs + wid * 1024 + 512), 16, 0, 0);
        __syncthreads();

        bf16x8 af[4], bfr[4];
#pragma unroll
        for (int m = 0; m < 4; ++m)
            af[m] = *reinterpret_cast<const bf16x8*>(As + (wm * 64 + m * 16 + lr) * 32 + kq);
#pragma unroll
        for (int n = 0; n < 4; ++n)
            bfr[n] = *reinterpret_cast<const bf16x8*>(Bs + (wn * 64 + n * 16 + lr) * 32 + kq);
#pragma unroll
        for (int m = 0; m < 4; ++m)
#pragma unroll
            for (int n = 0; n < 4; ++n)
                acc[m][n] = __builtin_amdgcn_mfma_f32_16x16x32_bf16(af[m], bfr[n], acc[m][n], 0, 0, 0);
    }

    const int lg = lane >> 4;
#pragma unroll
    for (int p = 0; p < 2; ++p) {
        int ncol = col0 + wn * 64 + p * 32 + lr;       // num column (fragment n=2p)
        int r = ((ncol >> 5) << 4) + lr;               // original r = b*1024 + d
#pragma unroll
        for (int m = 0; m < 4; ++m) {
            int trow = row0 + wm * 64 + m * 16 + lg * 4;
#pragma unroll
            for (int j = 0; j < 4; ++j) {
                int t = trow + j;
                float num = acc[m][2 * p][j];
                float den = acc[m][2 * p + 1][j];
                float qv = q[(size_t)t * R_DIM + r];
                float y = num / (den * (1.0f + __expf(-qv)));
                Y[(size_t)t * R_DIM + r] = (bf16_t)y;
            }
        }
    }
}

extern "C" void kernel_launch(void* const* d_in, const int* in_sizes, int n_in,
                              void* d_out, int out_size, void* d_ws, size_t ws_size,
                              hipStream_t stream) {
    const float* data     = (const float*)d_in[0];  // [T,B,D]
    const float* W_qkv    = (const float*)d_in[1];  // [D,3D]
    const float* b_qkv    = (const float*)d_in[2];  // [3D]
    const float* pos_bias = (const float*)d_in[3];  // [T,T]
    const float* W_out    = (const float*)d_in[4];  // [D,D]
    const float* b_out    = (const float*)d_in[5];  // [D]
    float* out = (float*)d_out;

    char* ws = (char*)d_ws;
    const size_t MB = 1024 * 1024;
    bf16_t* data_bf = (bf16_t*)(ws + 0);         //  8 MB [4096][1024]
    bf16_t* WqkvT   = (bf16_t*)(ws + 8 * MB);    //  6 MB [3072][1024]
    bf16_t* WoutT   = (bf16_t*)(ws + 14 * MB);   //  2 MB [1024][1024]
    bf16_t* P_bf    = (bf16_t*)(ws + 16 * MB);   //  2 MB [1024][1024]
    float*  q_buf   = (float*) (ws + 18 * MB);   // 16 MB [4096][1024] (= [t*4096+r] flat)
    bf16_t* BndT    = (bf16_t*)(ws + 34 * MB);   // 16 MB [8192][1024] interleaved
    bf16_t* Y       = (bf16_t*)(ws + 0);         //  8 MB, aliases data_bf (dead after GEMM_kv)

    // 1. prep: all conversions
    k_prep<<<dim3(9216), dim3(256), 0, stream>>>(data, pos_bias, W_qkv, W_out,
                                                 data_bf, P_bf, WqkvT, WoutT);
    // 2. q = data @ Wq + b_q
    k_gemm<<<dim3(R_DIM / 128, D_DIM / 128), dim3(256), 0, stream>>>(
        data_bf, WqkvT, b_qkv, q_buf, R_DIM, D_DIM, D_DIM);
    // 3. kv GEMM fused -> BndT
    k_gemm_kv<<<dim3(D_DIM / 128, T_DIM / 128, B_DIM), dim3(256), 0, stream>>>(
        WqkvT, data_bf, BndT);
    // 4. GEMM2 fused: Y = sigmoid(q) * (P@EKV) / (P@EK)
    k_gemm_aft<<<dim3(T_DIM / 128, N_ND / 128), dim3(256), 0, stream>>>(
        P_bf, BndT, q_buf, Y);
    // 5. out = Y @ W_out + b_out
    k_gemm<<<dim3(R_DIM / 128, D_DIM / 128), dim3(256), 0, stream>>>(
        Y, WoutT, b_out, out, R_DIM, D_DIM, D_DIM);
}

// Round 6
// 195.379 us; speedup vs baseline: 1.0658x; 1.0658x over previous
//
#include <hip/hip_runtime.h>
#include <hip/hip_bf16.h>
#include <cstdint>
#include <cstddef>

// AFT forward, MI355X. Pipeline (5 dispatches):
//  1. prep   : data f32->bf16 | P=exp(pos_bias) bf16 | W_qkv^T split:
//              WqT [1024][1024] (q weights), WkvTi [2048][1024] k/v INTERLEAVED
//              (row rr_d(d)=((d>>4)<<5)+(d&15) <- Wk col d; rr_d+16 <- Wv col d)
//              | W_out^T bf16
//  2. GEMM_q : q f32 [i][d] = data_bf @ WqT^T + b_q   (k_gemm; q[t*4096+r] flat)
//  3. GEMM_kv2: standard 128^2 GEMM, A=WkvTi, B=data rows 4t+b (per-b grid.z);
//              frag pairs (m=2p,2p+1) = k,v for SAME d -> epilogue writes
//              BndT[rr][t]=exp(k)*v (num), BndT[rr+16][t]=exp(k) (den),
//              rr=((r>>4)<<5)+(r&15), r=b*1024+d. Single acc, 2 LDS bufs.
//  4. GEMM2f : Y bf16 [t*4096+r] = sigmoid(q)*[P@EKV]/[P@EK]  (fused epilogue)
//  5. GEMM3  : out f32 [4096][1024] = Y @ W_out^T + b_out     (k_gemm)
// GEMM = m97 structure: 128x128 tile, BK=32, 4 waves, mfma_f32_16x16x32_bf16,
// global_load_lds width-16 staging, linear LDS.

typedef __bf16 bf16_t;
typedef __attribute__((ext_vector_type(8))) __bf16 bf16x8;
typedef __attribute__((ext_vector_type(4))) __bf16 bf16x4;
typedef __attribute__((ext_vector_type(4))) float floatx4;

#define T_DIM 1024
#define B_DIM 4
#define D_DIM 1024
#define R_DIM (T_DIM * B_DIM)   // 4096
#define N_QKV (3 * D_DIM)       // 3072
#define N_ND  (2 * R_DIM)       // 8192

// ---------------- prep: all input conversions in one dispatch ----------------
// blocks [0,4096)    : data f32 -> bf16
// blocks [4096,5120) : P = exp(pos_bias) -> bf16
// blocks [5120,8192) : tconv W_qkv -> WqT / WkvTi (interleaved remap)
// blocks [8192,9216) : tconv W_out -> WoutT
__global__ void k_prep(const float* __restrict__ data, const float* __restrict__ pos_bias,
                       const float* __restrict__ W_qkv, const float* __restrict__ W_out,
                       bf16_t* __restrict__ data_bf, bf16_t* __restrict__ P_bf,
                       bf16_t* __restrict__ WqT, bf16_t* __restrict__ WkvTi,
                       bf16_t* __restrict__ WoutT) {
    __shared__ float s[32][33];
    const int bid = blockIdx.x, tid = threadIdx.x;
    if (bid < 5120) {
        const float* in = (bid < 4096) ? data : pos_bias;
        bf16_t* out = (bid < 4096) ? data_bf : P_bf;
        int bb = (bid < 4096) ? bid : bid - 4096;
        int do_exp = (bid >= 4096);
        int i = (bb * 256 + tid) * 4;
        float4 v = *reinterpret_cast<const float4*>(in + i);
        bf16x4 o;
        if (do_exp) {
            o[0] = (bf16_t)__expf(v.x); o[1] = (bf16_t)__expf(v.y);
            o[2] = (bf16_t)__expf(v.z); o[3] = (bf16_t)__expf(v.w);
        } else {
            o[0] = (bf16_t)v.x; o[1] = (bf16_t)v.y;
            o[2] = (bf16_t)v.z; o[3] = (bf16_t)v.w;
        }
        *reinterpret_cast<bf16x4*>(out + i) = o;
    } else if (bid < 8192) {
        // W_qkv [1024][3072] transpose+convert with q/kv split + kv interleave
        int idx = bid - 5120;                       // 3072 blocks = 96 x 32
        int n0 = (idx % 96) * 32, k0 = (idx / 96) * 32;
        int tx = tid & 31, ty = tid >> 5;
#pragma unroll
        for (int i = 0; i < 4; ++i)
            s[ty + i * 8][tx] = W_qkv[(size_t)(k0 + ty + i * 8) * N_QKV + n0 + tx];
        __syncthreads();
#pragma unroll
        for (int i = 0; i < 4; ++i) {
            int n = n0 + ty + i * 8;
            bf16_t val = (bf16_t)s[tx][ty + i * 8];
            bf16_t* dst; size_t row;
            if (n < 1024)      { dst = WqT;   row = n; }
            else if (n < 2048) { int d = n - 1024; dst = WkvTi; row = ((d >> 4) << 5) + (d & 15); }
            else               { int d = n - 2048; dst = WkvTi; row = ((d >> 4) << 5) + (d & 15) + 16; }
            dst[row * D_DIM + k0 + tx] = val;
        }
    } else {
        int idx = bid - 8192;                       // 1024 blocks = 32 x 32
        int n0 = (idx % 32) * 32, k0 = (idx / 32) * 32;
        int tx = tid & 31, ty = tid >> 5;
#pragma unroll
        for (int i = 0; i < 4; ++i)
            s[ty + i * 8][tx] = W_out[(size_t)(k0 + ty + i * 8) * D_DIM + n0 + tx];
        __syncthreads();
#pragma unroll
        for (int i = 0; i < 4; ++i)
            WoutT[(size_t)(n0 + ty + i * 8) * D_DIM + k0 + tx] = (bf16_t)s[tx][ty + i * 8];
    }
}

// ---------------- GEMM: C[M][N] = A[M][K] @ BT[N][K]^T (+bias) ----------------
__global__ __launch_bounds__(256)
void k_gemm(const bf16_t* __restrict__ A, const bf16_t* __restrict__ BT,
            const float* __restrict__ bias, float* __restrict__ C,
            int M, int N, int K) {
    __shared__ __align__(16) bf16_t As[128 * 32];
    __shared__ __align__(16) bf16_t Bs[128 * 32];
    const int tid = threadIdx.x;
    const int wid = tid >> 6, lane = tid & 63;
    const int wm = wid >> 1, wn = wid & 1;
    const int row0 = blockIdx.x * 128, col0 = blockIdx.y * 128;

    floatx4 acc[4][4];
#pragma unroll
    for (int m = 0; m < 4; ++m)
#pragma unroll
        for (int n = 0; n < 4; ++n) acc[m][n] = (floatx4){0.f, 0.f, 0.f, 0.f};

    const int lr = lane & 15;
    const int kq = (lane >> 4) * 8;
    const int e0 = wid * 1024 + lane * 8;
    const int ra0 = e0 >> 5, kk0 = e0 & 31;
    const int ra1 = (e0 + 512) >> 5, kk1 = (e0 + 512) & 31;

    const bf16_t* Ab = A + (size_t)row0 * K;
    const bf16_t* Bb = BT + (size_t)col0 * K;

    for (int kt = 0; kt < K; kt += 32) {
        __syncthreads();
        __builtin_amdgcn_global_load_lds(
            (const __attribute__((address_space(1))) void*)(Ab + (size_t)ra0 * K + kt + kk0),
            (__attribute__((address_space(3))) void*)(As + wid * 1024), 16, 0, 0);
        __builtin_amdgcn_global_load_lds(
            (const __attribute__((address_space(1))) void*)(Ab + (size_t)ra1 * K + kt + kk1),
            (__attribute__((address_space(3))) void*)(As + wid * 1024 + 512), 16, 0, 0);
        __builtin_amdgcn_global_load_lds(
            (const __attribute__((address_space(1))) void*)(Bb + (size_t)ra0 * K + kt + kk0),
            (__attribute__((address_space(3))) void*)(Bs + wid * 1024), 16, 0, 0);
        __builtin_amdgcn_global_load_lds(
            (const __attribute__((address_space(1))) void*)(Bb + (size_t)ra1 * K + kt + kk1),
            (__attribute__((address_space(3))) void*)(Bs + wid * 1024 + 512), 16, 0, 0);
        __syncthreads();

        bf16x8 af[4], bfr[4];
#pragma unroll
        for (int m = 0; m < 4; ++m)
            af[m] = *reinterpret_cast<const bf16x8*>(As + (wm * 64 + m * 16 + lr) * 32 + kq);
#pragma unroll
        for (int n = 0; n < 4; ++n)
            bfr[n] = *reinterpret_cast<const bf16x8*>(Bs + (wn * 64 + n * 16 + lr) * 32 + kq);
#pragma unroll
        for (int m = 0; m < 4; ++m)
#pragma unroll
            for (int n = 0; n < 4; ++n)
                acc[m][n] = __builtin_amdgcn_mfma_f32_16x16x32_bf16(af[m], bfr[n], acc[m][n], 0, 0, 0);
    }

    const int lg = lane >> 4;
#pragma unroll
    for (int n = 0; n < 4; ++n) {
        int col = col0 + wn * 64 + n * 16 + lr;
        float bv = bias ? bias[col] : 0.0f;
#pragma unroll
        for (int m = 0; m < 4; ++m) {
            int row = row0 + wm * 64 + m * 16 + lg * 4;
            float* Cp = C + (size_t)row * N + col;
#pragma unroll
            for (int j = 0; j < 4; ++j) Cp[(size_t)j * N] = acc[m][n][j] + bv;
        }
    }
}

// ---------------- GEMM_kv2: interleaved k/v GEMM -> BndT num/den directly ----------
// A = WkvTi [2048][1024] (32-row groups [16 k | 16 v], same d). B rows = data 4t+b.
// Standard single-acc 128^2 tile. grid (16, 8, 4) = 512 blocks.
__global__ __launch_bounds__(256)
void k_gemm_kv2(const bf16_t* __restrict__ WkvTi, const bf16_t* __restrict__ data_bf,
                const float* __restrict__ b_qkv, bf16_t* __restrict__ BndT) {
    const int K = D_DIM;
    __shared__ __align__(16) bf16_t As[128 * 32];
    __shared__ __align__(16) bf16_t Bs[128 * 32];
    const int tid = threadIdx.x;
    const int wid = tid >> 6, lane = tid & 63;
    const int wm = wid >> 1, wn = wid & 1;
    const int row0 = blockIdx.x * 128;   // WkvTi row (interleaved k/v)
    const int col0 = blockIdx.y * 128;   // t
    const int b = blockIdx.z;

    floatx4 acc[4][4];
#pragma unroll
    for (int m = 0; m < 4; ++m)
#pragma unroll
        for (int n = 0; n < 4; ++n) acc[m][n] = (floatx4){0.f, 0.f, 0.f, 0.f};

    const int lr = lane & 15;
    const int kq = (lane >> 4) * 8;
    const int e0 = wid * 1024 + lane * 8;
    const int ra0 = e0 >> 5, kk0 = e0 & 31;
    const int ra1 = (e0 + 512) >> 5, kk1 = (e0 + 512) & 31;

    const bf16_t* Ab = WkvTi + (size_t)row0 * K;
    const size_t bg0 = ((size_t)(col0 + ra0) * 4 + b) * D_DIM;
    const size_t bg1 = ((size_t)(col0 + ra1) * 4 + b) * D_DIM;

    for (int kt = 0; kt < K; kt += 32) {
        __syncthreads();
        __builtin_amdgcn_global_load_lds(
            (const __attribute__((address_space(1))) void*)(Ab + (size_t)ra0 * K + kt + kk0),
            (__attribute__((address_space(3))) void*)(As + wid * 1024), 16, 0, 0);
        __builtin_amdgcn_global_load_lds(
            (const __attribute__((address_space(1))) void*)(Ab + (size_t)ra1 * K + kt + kk1),
            (__attribute__((address_space(3))) void*)(As + wid * 1024 + 512), 16, 0, 0);
        __builtin_amdgcn_global_load_lds(
            (const __attribute__((address_space(1))) void*)(data_bf + bg0 + kt + kk0),
            (__attribute__((address_space(3))) void*)(Bs + wid * 1024), 16, 0, 0);
        __builtin_amdgcn_global_load_lds(
            (const __attribute__((address_space(1))) void*)(data_bf + bg1 + kt + kk1),
            (__attribute__((address_space(3))) void*)(Bs + wid * 1024 + 512), 16, 0, 0);
        __syncthreads();

        bf16x8 af[4], bfr[4];
#pragma unroll
        for (int m = 0; m < 4; ++m)
            af[m] = *reinterpret_cast<const bf16x8*>(As + (wm * 64 + m * 16 + lr) * 32 + kq);
#pragma unroll
        for (int n = 0; n < 4; ++n)
            bfr[n] = *reinterpret_cast<const bf16x8*>(Bs + (wn * 64 + n * 16 + lr) * 32 + kq);
#pragma unroll
        for (int m = 0; m < 4; ++m)
#pragma unroll
            for (int n = 0; n < 4; ++n)
                acc[m][n] = __builtin_amdgcn_mfma_f32_16x16x32_bf16(af[m], bfr[n], acc[m][n], 0, 0, 0);
    }

    // epilogue: pairs (m=2p, 2p+1) = (k, v) for the same d
    const int lg = lane >> 4;
#pragma unroll
    for (int p = 0; p < 2; ++p) {
#pragma unroll
        for (int j = 0; j < 4; ++j) {
            int gk = row0 + wm * 64 + p * 32 + lg * 4 + j;  // k-row in WkvTi space
            int d = ((gk >> 5) << 4) + (lg * 4 + j);
            float bk = b_qkv[D_DIM + d];
            float bv = b_qkv[2 * D_DIM + d];
            int r = b * D_DIM + d;
            int rr = ((r >> 4) << 5) + (r & 15);
#pragma unroll
            for (int n = 0; n < 4; ++n) {
                int t = col0 + wn * 64 + n * 16 + lr;
                float e = __expf(acc[2 * p][n][j] + bk);
                float vv = acc[2 * p + 1][n][j] + bv;
                BndT[(size_t)rr * T_DIM + t] = (bf16_t)(e * vv);        // num
                BndT[(size_t)(rr + 16) * T_DIM + t] = (bf16_t)e;        // den
            }
        }
    }
}

// ---------------- GEMM2 fused: Y = sigmoid(q) * (P@EKV)/(P@EK) ----------------
__global__ __launch_bounds__(256)
void k_gemm_aft(const bf16_t* __restrict__ A, const bf16_t* __restrict__ BT,
                const float* __restrict__ q, bf16_t* __restrict__ Y) {
    const int K = T_DIM;
    __shared__ __align__(16) bf16_t As[128 * 32];
    __shared__ __align__(16) bf16_t Bs[128 * 32];
    const int tid = threadIdx.x;
    const int wid = tid >> 6, lane = tid & 63;
    const int wm = wid >> 1, wn = wid & 1;
    const int row0 = blockIdx.x * 128, col0 = blockIdx.y * 128;

    floatx4 acc[4][4];
#pragma unroll
    for (int m = 0; m < 4; ++m)
#pragma unroll
        for (int n = 0; n < 4; ++n) acc[m][n] = (floatx4){0.f, 0.f, 0.f, 0.f};

    const int lr = lane & 15;
    const int kq = (lane >> 4) * 8;
    const int e0 = wid * 1024 + lane * 8;
    const int ra0 = e0 >> 5, kk0 = e0 & 31;
    const int ra1 = (e0 + 512) >> 5, kk1 = (e0 + 512) & 31;

    const bf16_t* Ab = A + (size_t)row0 * K;
    const bf16_t* Bb = BT + (size_t)col0 * K;

    for (int kt = 0; kt < K; kt += 32) {
        __syncthreads();
        __builtin_amdgcn_global_load_lds(
            (const __attribute__((address_space(1))) void*)(Ab + (size_t)ra0 * K + kt + kk0),
            (__attribute__((address_space(3))) void*)(As + wid * 1024), 16, 0, 0);
        __builtin_amdgcn_global_load_lds(
            (const __attribute__((address_space(1))) void*)(Ab + (size_t)ra1 * K + kt + kk1),
            (__attribute__((address_space(3))) void*)(As + wid * 1024 + 512), 16, 0, 0);
        __builtin_amdgcn_global_load_lds(
            (const __attribute__((address_space(1))) void*)(Bb + (size_t)ra0 * K + kt + kk0),
            (__attribute__((address_space(3))) void*)(Bs + wid * 1024), 16, 0, 0);
        __builtin_amdgcn_global_load_lds(
            (const __attribute__((address_space(1))) void*)(Bb + (size_t)ra1 * K + kt + kk1),
            (__attribute__((address_space(3))) void*)(Bs + wid * 1024 + 512), 16, 0, 0);
        __syncthreads();

        bf16x8 af[4], bfr[4];
#pragma unroll
        for (int m = 0; m < 4; ++m)
            af[m] = *reinterpret_cast<const bf16x8*>(As + (wm * 64 + m * 16 + lr) * 32 + kq);
#pragma unroll
        for (int n = 0; n < 4; ++n)
            bfr[n] = *reinterpret_cast<const bf16x8*>(Bs + (wn * 64 + n * 16 + lr) * 32 + kq);
#pragma unroll
        for (int m = 0; m < 4; ++m)
#pragma unroll
            for (int n = 0; n < 4; ++n)
                acc[m][n] = __builtin_amdgcn_mfma_f32_16x16x32_bf16(af[m], bfr[n], acc[m][n], 0, 0, 0);
    }

    const int lg = lane >> 4;
#pragma unroll
    for (int p = 0; p < 2; ++p) {
        int ncol = col0 + wn * 64 + p * 32 + lr;       // num column (fragment n=2p)
        int r = ((ncol >> 5) << 4) + lr;               // original r = b*1024 + d
#pragma unroll
        for (int m = 0; m < 4; ++m) {
            int trow = row0 + wm * 64 + m * 16 + lg * 4;
#pragma unroll
            for (int j = 0; j < 4; ++j) {
                int t = trow + j;
                float num = acc[m][2 * p][j];
                float den = acc[m][2 * p + 1][j];
                float qv = q[(size_t)t * R_DIM + r];
                float y = num / (den * (1.0f + __expf(-qv)));
                Y[(size_t)t * R_DIM + r] = (bf16_t)y;
            }
        }
    }
}

extern "C" void kernel_launch(void* const* d_in, const int* in_sizes, int n_in,
                              void* d_out, int out_size, void* d_ws, size_t ws_size,
                              hipStream_t stream) {
    const float* data     = (const float*)d_in[0];  // [T,B,D]
    const float* W_qkv    = (const float*)d_in[1];  // [D,3D]
    const float* b_qkv    = (const float*)d_in[2];  // [3D]
    const float* pos_bias = (const float*)d_in[3];  // [T,T]
    const float* W_out    = (const float*)d_in[4];  // [D,D]
    const float* b_out    = (const float*)d_in[5];  // [D]
    float* out = (float*)d_out;

    char* ws = (char*)d_ws;
    const size_t MB = 1024 * 1024;
    bf16_t* data_bf = (bf16_t*)(ws + 0);         //  8 MB [4096][1024]
    bf16_t* WqT     = (bf16_t*)(ws + 8 * MB);    //  2 MB [1024][1024]
    bf16_t* WkvTi   = (bf16_t*)(ws + 10 * MB);   //  4 MB [2048][1024] interleaved
    bf16_t* WoutT   = (bf16_t*)(ws + 14 * MB);   //  2 MB [1024][1024]
    bf16_t* P_bf    = (bf16_t*)(ws + 16 * MB);   //  2 MB [1024][1024]
    float*  q_buf   = (float*) (ws + 18 * MB);   // 16 MB [t*4096+r] flat
    bf16_t* BndT    = (bf16_t*)(ws + 34 * MB);   // 16 MB [8192][1024] interleaved
    bf16_t* Y       = (bf16_t*)(ws + 0);         //  8 MB, aliases data_bf (dead after kv2)

    // 1. prep: all conversions + weight split/interleave
    k_prep<<<dim3(9216), dim3(256), 0, stream>>>(data, pos_bias, W_qkv, W_out,
                                                 data_bf, P_bf, WqT, WkvTi, WoutT);
    // 2. q = data @ Wq + b_q   (writes q[t*4096+r])
    k_gemm<<<dim3(R_DIM / 128, D_DIM / 128), dim3(256), 0, stream>>>(
        data_bf, WqT, b_qkv, q_buf, R_DIM, D_DIM, D_DIM);
    // 3. kv interleaved GEMM -> BndT num/den
    k_gemm_kv2<<<dim3(2 * D_DIM / 128, T_DIM / 128, B_DIM), dim3(256), 0, stream>>>(
        WkvTi, data_bf, b_qkv, BndT);
    // 4. GEMM2 fused: Y = sigmoid(q) * (P@EKV) / (P@EK)
    k_gemm_aft<<<dim3(T_DIM / 128, N_ND / 128), dim3(256), 0, stream>>>(
        P_bf, BndT, q_buf, Y);
    // 5. out = Y @ W_out + b_out
    k_gemm<<<dim3(R_DIM / 128, D_DIM / 128), dim3(256), 0, stream>>>(
        Y, WoutT, b_out, out, R_DIM, D_DIM, D_DIM);
}

// Round 8
// 178.195 us; speedup vs baseline: 1.1686x; 1.0964x over previous
//
#include <hip/hip_runtime.h>
#include <hip/hip_bf16.h>
#include <cstdint>
#include <cstddef>

// AFT forward, MI355X. Pipeline (4 dispatches):
//  1. prep    : data f32->bf16 | P=exp(pos_bias) bf16 | W_qkv^T split into
//               WqT [1024][1024] + WkvTi [2048][1024] (k/v interleaved 16-row
//               groups: row rr_d(d)=((d>>4)<<5)+(d&15) <- Wk col d, rr_d+16 <- Wv)
//               | W_out^T bf16
//  2. qkv     : GRID-UNION kernel, 768 blocks:
//               blocks [0,256)  : q f32 = data_bf @ WqT^T + b_q  (q[(t*4+b)*1024+d])
//               blocks [256,768): kv GEMM (A=WkvTi, B=data rows 4t+b) ->
//               epilogue BndT[rr][t]=exp(k)*v, BndT[rr+16][t]=exp(k),
//               rr=((r>>4)<<5)+(r&15), r=b*1024+d
//  3. GEMM2f  : Y bf16 [t*4096+r] = sigmoid(q)*[P@EKV]/[P@EK] (fused epilogue)
//  4. GEMM3   : out f32 = Y @ W_out^T + b_out
// All GEMMs: m97 structure (128x128 tile, BK=32, 4 waves, mfma_f32_16x16x32_bf16,
// global_load_lds width-16, linear LDS) via shared mfma_loop body.

typedef __bf16 bf16_t;
typedef __attribute__((ext_vector_type(8))) __bf16 bf16x8;
typedef __attribute__((ext_vector_type(4))) __bf16 bf16x4;
typedef __attribute__((ext_vector_type(4))) float floatx4;

#define T_DIM 1024
#define B_DIM 4
#define D_DIM 1024
#define R_DIM (T_DIM * B_DIM)   // 4096
#define N_QKV (3 * D_DIM)       // 3072
#define N_ND  (2 * R_DIM)       // 8192

// ---------------- prep: all input conversions in one dispatch ----------------
__global__ void k_prep(const float* __restrict__ data, const float* __restrict__ pos_bias,
                       const float* __restrict__ W_qkv, const float* __restrict__ W_out,
                       bf16_t* __restrict__ data_bf, bf16_t* __restrict__ P_bf,
                       bf16_t* __restrict__ WqT, bf16_t* __restrict__ WkvTi,
                       bf16_t* __restrict__ WoutT) {
    __shared__ float s[32][33];
    const int bid = blockIdx.x, tid = threadIdx.x;
    if (bid < 5120) {
        const float* in = (bid < 4096) ? data : pos_bias;
        bf16_t* out = (bid < 4096) ? data_bf : P_bf;
        int bb = (bid < 4096) ? bid : bid - 4096;
        int do_exp = (bid >= 4096);
        int i = (bb * 256 + tid) * 4;
        float4 v = *reinterpret_cast<const float4*>(in + i);
        bf16x4 o;
        if (do_exp) {
            o[0] = (bf16_t)__expf(v.x); o[1] = (bf16_t)__expf(v.y);
            o[2] = (bf16_t)__expf(v.z); o[3] = (bf16_t)__expf(v.w);
        } else {
            o[0] = (bf16_t)v.x; o[1] = (bf16_t)v.y;
            o[2] = (bf16_t)v.z; o[3] = (bf16_t)v.w;
        }
        *reinterpret_cast<bf16x4*>(out + i) = o;
    } else if (bid < 8192) {
        int idx = bid - 5120;                       // 3072 blocks = 96 x 32
        int n0 = (idx % 96) * 32, k0 = (idx / 96) * 32;
        int tx = tid & 31, ty = tid >> 5;
#pragma unroll
        for (int i = 0; i < 4; ++i)
            s[ty + i * 8][tx] = W_qkv[(size_t)(k0 + ty + i * 8) * N_QKV + n0 + tx];
        __syncthreads();
#pragma unroll
        for (int i = 0; i < 4; ++i) {
            int n = n0 + ty + i * 8;
            bf16_t val = (bf16_t)s[tx][ty + i * 8];
            bf16_t* dst; size_t row;
            if (n < 1024)      { dst = WqT;   row = n; }
            else if (n < 2048) { int d = n - 1024; dst = WkvTi; row = ((d >> 4) << 5) + (d & 15); }
            else               { int d = n - 2048; dst = WkvTi; row = ((d >> 4) << 5) + (d & 15) + 16; }
            dst[row * D_DIM + k0 + tx] = val;
        }
    } else {
        int idx = bid - 8192;                       // 1024 blocks = 32 x 32
        int n0 = (idx % 32) * 32, k0 = (idx / 32) * 32;
        int tx = tid & 31, ty = tid >> 5;
#pragma unroll
        for (int i = 0; i < 4; ++i)
            s[ty + i * 8][tx] = W_out[(size_t)(k0 + ty + i * 8) * D_DIM + n0 + tx];
        __syncthreads();
#pragma unroll
        for (int i = 0; i < 4; ++i)
            WoutT[(size_t)(n0 + ty + i * 8) * D_DIM + k0 + tx] = (bf16_t)s[tx][ty + i * 8];
    }
}

// ---------------- shared m97 GEMM main loop ----------------
__device__ __forceinline__ void gload16(const bf16_t* src, bf16_t* dst) {
    __builtin_amdgcn_global_load_lds(
        (const __attribute__((address_space(1))) void*)src,
        (__attribute__((address_space(3))) void*)dst, 16, 0, 0);
}

// aSrc0/1, bSrc0/1: per-thread global source addresses at kt=0 (incl. row*K + kk).
__device__ __forceinline__ void mfma_loop(
    const bf16_t* __restrict__ aSrc0, const bf16_t* __restrict__ aSrc1,
    const bf16_t* __restrict__ bSrc0, const bf16_t* __restrict__ bSrc1,
    bf16_t* As, bf16_t* Bs, int wid, int lane, int K, floatx4 (&acc)[4][4]) {
    const int lr = lane & 15, kq = (lane >> 4) * 8;
    const int wm = wid >> 1, wn = wid & 1;
    for (int kt = 0; kt < K; kt += 32) {
        __syncthreads();
        gload16(aSrc0 + kt, As + wid * 1024);
        gload16(aSrc1 + kt, As + wid * 1024 + 512);
        gload16(bSrc0 + kt, Bs + wid * 1024);
        gload16(bSrc1 + kt, Bs + wid * 1024 + 512);
        __syncthreads();
        bf16x8 af[4], bfr[4];
#pragma unroll
        for (int m = 0; m < 4; ++m)
            af[m] = *reinterpret_cast<const bf16x8*>(As + (wm * 64 + m * 16 + lr) * 32 + kq);
#pragma unroll
        for (int n = 0; n < 4; ++n)
            bfr[n] = *reinterpret_cast<const bf16x8*>(Bs + (wn * 64 + n * 16 + lr) * 32 + kq);
#pragma unroll
        for (int m = 0; m < 4; ++m)
#pragma unroll
            for (int n = 0; n < 4; ++n)
                acc[m][n] = __builtin_amdgcn_mfma_f32_16x16x32_bf16(af[m], bfr[n], acc[m][n], 0, 0, 0);
    }
}

#define GEMM_PREAMBLE(K)                                              \
    __shared__ __align__(16) bf16_t As[128 * 32];                     \
    __shared__ __align__(16) bf16_t Bs[128 * 32];                     \
    const int tid = threadIdx.x;                                      \
    const int wid = tid >> 6, lane = tid & 63;                        \
    const int wm = wid >> 1, wn = wid & 1;                            \
    floatx4 acc[4][4];                                                \
    _Pragma("unroll") for (int m = 0; m < 4; ++m)                     \
        _Pragma("unroll") for (int n = 0; n < 4; ++n)                 \
            acc[m][n] = (floatx4){0.f, 0.f, 0.f, 0.f};                \
    const int lr = lane & 15;                                         \
    const int e0 = wid * 1024 + lane * 8;                             \
    const int ra0 = e0 >> 5, kk0 = e0 & 31;                           \
    const int ra1 = (e0 + 512) >> 5, kk1 = (e0 + 512) & 31;           \
    const int lg = lane >> 4; (void)lg; (void)K;

// ---------------- generic GEMM: C[M][N] = A @ BT^T (+bias), f32 out ----------------
__global__ __launch_bounds__(256)
void k_gemm(const bf16_t* __restrict__ A, const bf16_t* __restrict__ BT,
            const float* __restrict__ bias, float* __restrict__ C,
            int M, int N, int K) {
    GEMM_PREAMBLE(K)
    const int row0 = blockIdx.x * 128, col0 = blockIdx.y * 128;
    mfma_loop(A + (size_t)(row0 + ra0) * K + kk0, A + (size_t)(row0 + ra1) * K + kk1,
              BT + (size_t)(col0 + ra0) * K + kk0, BT + (size_t)(col0 + ra1) * K + kk1,
              As, Bs, wid, lane, K, acc);
#pragma unroll
    for (int n = 0; n < 4; ++n) {
        int col = col0 + wn * 64 + n * 16 + lr;
        float bv = bias ? bias[col] : 0.0f;
#pragma unroll
        for (int m = 0; m < 4; ++m) {
            int row = row0 + wm * 64 + m * 16 + lg * 4;
            float* Cp = C + (size_t)row * N + col;
#pragma unroll
            for (int j = 0; j < 4; ++j) Cp[(size_t)j * N] = acc[m][n][j] + bv;
        }
    }
}

// ---------------- qkv grid-union kernel ----------------
// blocks [0,256):   q GEMM  (M=4096 data rows x N=1024 WqT rows), q_buf f32
// blocks [256,768): kv GEMM (M=2048 WkvTi rows x N=1024 t, per-b), BndT bf16
__global__ __launch_bounds__(256)
void k_gemm_qkv(const bf16_t* __restrict__ data_bf, const bf16_t* __restrict__ WqT,
                const bf16_t* __restrict__ WkvTi, const float* __restrict__ b_qkv,
                float* __restrict__ q_buf, bf16_t* __restrict__ BndT) {
    const int K = D_DIM;
    GEMM_PREAMBLE(K)
    const int bid = blockIdx.x;
    if (bid < 256) {
        // ---- q path: A = data_bf, B^T = WqT ----
        const int row0 = (bid >> 3) * 128, col0 = (bid & 7) * 128;
        mfma_loop(data_bf + (size_t)(row0 + ra0) * K + kk0,
                  data_bf + (size_t)(row0 + ra1) * K + kk1,
                  WqT + (size_t)(col0 + ra0) * K + kk0,
                  WqT + (size_t)(col0 + ra1) * K + kk1,
                  As, Bs, wid, lane, K, acc);
#pragma unroll
        for (int n = 0; n < 4; ++n) {
            int col = col0 + wn * 64 + n * 16 + lr;
            float bv = b_qkv[col];
#pragma unroll
            for (int m = 0; m < 4; ++m) {
                int row = row0 + wm * 64 + m * 16 + lg * 4;   // data row = t*4+b
                float* Cp = q_buf + (size_t)row * D_DIM + col;
#pragma unroll
                for (int j = 0; j < 4; ++j) Cp[(size_t)j * D_DIM] = acc[m][n][j] + bv;
            }
        }
    } else {
        // ---- kv path: A = WkvTi (interleaved), B rows = data rows 4t+b ----
        const int idx = bid - 256;
        const int b = idx >> 7;
        const int row0 = ((idx & 127) >> 3) * 128;   // WkvTi row tile (16 tiles)
        const int col0 = (idx & 7) * 128;            // t tile (8 tiles)
        mfma_loop(WkvTi + (size_t)(row0 + ra0) * K + kk0,
                  WkvTi + (size_t)(row0 + ra1) * K + kk1,
                  data_bf + ((size_t)(col0 + ra0) * 4 + b) * D_DIM + kk0,
                  data_bf + ((size_t)(col0 + ra1) * 4 + b) * D_DIM + kk1,
                  As, Bs, wid, lane, K, acc);
        // epilogue: pairs (m=2p, 2p+1) = (k, v) for the same d
#pragma unroll
        for (int p = 0; p < 2; ++p) {
#pragma unroll
            for (int j = 0; j < 4; ++j) {
                int gk = row0 + wm * 64 + p * 32 + lg * 4 + j;  // k-row in WkvTi space
                int d = ((gk >> 5) << 4) + (lg * 4 + j);
                float bk = b_qkv[D_DIM + d];
                float bv = b_qkv[2 * D_DIM + d];
                int r = b * D_DIM + d;
                int rr = ((r >> 4) << 5) + (r & 15);
#pragma unroll
                for (int n = 0; n < 4; ++n) {
                    int t = col0 + wn * 64 + n * 16 + lr;
                    float e = __expf(acc[2 * p][n][j] + bk);
                    float vv = acc[2 * p + 1][n][j] + bv;
                    BndT[(size_t)rr * T_DIM + t] = (bf16_t)(e * vv);        // num
                    BndT[(size_t)(rr + 16) * T_DIM + t] = (bf16_t)e;        // den
                }
            }
        }
    }
}

// ---------------- GEMM2 fused: Y = sigmoid(q) * (P@EKV)/(P@EK) ----------------
__global__ __launch_bounds__(256)
void k_gemm_aft(const bf16_t* __restrict__ A, const bf16_t* __restrict__ BT,
                const float* __restrict__ q, bf16_t* __restrict__ Y) {
    const int K = T_DIM;
    GEMM_PREAMBLE(K)
    const int row0 = blockIdx.x * 128, col0 = blockIdx.y * 128;
    mfma_loop(A + (size_t)(row0 + ra0) * K + kk0, A + (size_t)(row0 + ra1) * K + kk1,
              BT + (size_t)(col0 + ra0) * K + kk0, BT + (size_t)(col0 + ra1) * K + kk1,
              As, Bs, wid, lane, K, acc);
#pragma unroll
    for (int p = 0; p < 2; ++p) {
        int ncol = col0 + wn * 64 + p * 32 + lr;       // num column (fragment n=2p)
        int r = ((ncol >> 5) << 4) + lr;               // original r = b*1024 + d
#pragma unroll
        for (int m = 0; m < 4; ++m) {
            int trow = row0 + wm * 64 + m * 16 + lg * 4;
#pragma unroll
            for (int j = 0; j < 4; ++j) {
                int t = trow + j;
                float num = acc[m][2 * p][j];
                float den = acc[m][2 * p + 1][j];
                float qv = q[(size_t)t * R_DIM + r];
                float y = num / (den * (1.0f + __expf(-qv)));
                Y[(size_t)t * R_DIM + r] = (bf16_t)y;
            }
        }
    }
}

extern "C" void kernel_launch(void* const* d_in, const int* in_sizes, int n_in,
                              void* d_out, int out_size, void* d_ws, size_t ws_size,
                              hipStream_t stream) {
    const float* data     = (const float*)d_in[0];  // [T,B,D]
    const float* W_qkv    = (const float*)d_in[1];  // [D,3D]
    const float* b_qkv    = (const float*)d_in[2];  // [3D]
    const float* pos_bias = (const float*)d_in[3];  // [T,T]
    const float* W_out    = (const float*)d_in[4];  // [D,D]
    const float* b_out    = (const float*)d_in[5];  // [D]
    float* out = (float*)d_out;

    char* ws = (char*)d_ws;
    const size_t MB = 1024 * 1024;
    bf16_t* data_bf = (bf16_t*)(ws + 0);         //  8 MB [4096][1024]
    bf16_t* WqT     = (bf16_t*)(ws + 8 * MB);    //  2 MB [1024][1024]
    bf16_t* WkvTi   = (bf16_t*)(ws + 10 * MB);   //  4 MB [2048][1024] interleaved
    bf16_t* WoutT   = (bf16_t*)(ws + 14 * MB);   //  2 MB [1024][1024]
    bf16_t* P_bf    = (bf16_t*)(ws + 16 * MB);   //  2 MB [1024][1024]
    float*  q_buf   = (float*) (ws + 18 * MB);   // 16 MB q[(t*4+b)*1024+d]
    bf16_t* BndT    = (bf16_t*)(ws + 34 * MB);   // 16 MB [8192][1024] interleaved
    bf16_t* Y       = (bf16_t*)(ws + 0);         //  8 MB, aliases data_bf (dead after qkv)

    // 1. prep: all conversions + weight split/interleave
    k_prep<<<dim3(9216), dim3(256), 0, stream>>>(data, pos_bias, W_qkv, W_out,
                                                 data_bf, P_bf, WqT, WkvTi, WoutT);
    // 2. q + kv grid-union GEMM
    k_gemm_qkv<<<dim3(768), dim3(256), 0, stream>>>(data_bf, WqT, WkvTi, b_qkv,
                                                    q_buf, BndT);
    // 3. GEMM2 fused: Y = sigmoid(q) * (P@EKV) / (P@EK)
    k_gemm_aft<<<dim3(T_DIM / 128, N_ND / 128), dim3(256), 0, stream>>>(
        P_bf, BndT, q_buf, Y);
    // 4. out = Y @ W_out + b_out
    k_gemm<<<dim3(R_DIM / 128, D_DIM / 128), dim3(256), 0, stream>>>(
        Y, WoutT, b_out, out, R_DIM, D_DIM, D_DIM);
}